// Round 5
// baseline (576.854 us; speedup 1.0000x reference)
//
#include <hip/hip_runtime.h>

#define F0 128
#define F1 64
#define F2 32

__device__ __forceinline__ int rfl(int v) { return __builtin_amdgcn_readfirstlane(v); }

// ---------------- degree ----------------
__global__ void deg_count(const int* __restrict__ dst, int* __restrict__ deg, int E) {
    int e = blockIdx.x * blockDim.x + threadIdx.x;
    if (e < E) atomicAdd(&deg[dst[e]], 1);
}

// ---------------- scan (3 kernels), dinv fused into scan1 ----------------
__global__ void scan1(const int* __restrict__ deg, float* __restrict__ dinv,
                      int* __restrict__ rowptr, int* __restrict__ bsum, int N) {
    __shared__ int s[256];
    int i = blockIdx.x * 256 + threadIdx.x;
    int v = (i < N) ? deg[i] : 0;
    if (i < N) dinv[i] = rsqrtf((float)(v + 1));  // +1 self-loop
    s[threadIdx.x] = v;
    __syncthreads();
    for (int off = 1; off < 256; off <<= 1) {
        int t = 0;
        if (threadIdx.x >= off) t = s[threadIdx.x - off];
        __syncthreads();
        if (threadIdx.x >= off) s[threadIdx.x] += t;
        __syncthreads();
    }
    if (i < N) rowptr[i] = s[threadIdx.x] - v;
    if (threadIdx.x == 255) bsum[blockIdx.x] = s[255];
}

__global__ void scan2(int* __restrict__ bsum, int* __restrict__ boff, int nb) {
    __shared__ int s[256];
    int v = (threadIdx.x < nb) ? bsum[threadIdx.x] : 0;
    s[threadIdx.x] = v;
    __syncthreads();
    for (int off = 1; off < 256; off <<= 1) {
        int t = 0;
        if (threadIdx.x >= off) t = s[threadIdx.x - off];
        __syncthreads();
        if (threadIdx.x >= off) s[threadIdx.x] += t;
        __syncthreads();
    }
    if (threadIdx.x < nb) boff[threadIdx.x] = s[threadIdx.x] - v;
}

// scan3 also copies the finalized rowptr into cursor (replaces d2d memcpy)
__global__ void scan3(int* __restrict__ rowptr, const int* __restrict__ boff,
                      int* __restrict__ cursor, int N) {
    int i = blockIdx.x * 256 + threadIdx.x;
    if (i < N) {
        int v = rowptr[i] + boff[blockIdx.x];
        rowptr[i] = v;
        cursor[i] = v;
    }
}

// ---------------- bucket: cursor pre-initialized to rowptr ----------------
__global__ void bucket(const int* __restrict__ src, const int* __restrict__ dst,
                       int* __restrict__ cursor, int* __restrict__ csr, int E) {
    int e = blockIdx.x * 256 + threadIdx.x;
    if (e < E) {
        int pos = atomicAdd(&cursor[dst[e]], 1);
        csr[pos] = src[e];
    }
}

// ---------------- GEMM1: xws1 = (x @ W1) * dinv[row]   [N,128]x[128,64] ----------------
// 64x64 tile, 4x4 per thread; W staged in two K-halves to stay under 64KB LDS.
__global__ __launch_bounds__(256) void gemm1(const float* __restrict__ x,
                                             const float* __restrict__ W1,
                                             const float* __restrict__ dinv,
                                             float* __restrict__ xws1, int N) {
    __shared__ float sx[64][132];   // +4 pad: bank-safe, 16B-aligned rows
    __shared__ float sW[64][64];    // one K-half of W1
    int tid = threadIdx.x;
    int row0 = blockIdx.x * 64;

    // stage x tile: 64 rows x 128 k = 2048 float4
    for (int i = tid; i < 2048; i += 256) {
        int r = i >> 5, kq = i & 31;
        int gr = row0 + r;
        float4 v = make_float4(0.f, 0.f, 0.f, 0.f);
        if (gr < N) v = ((const float4*)(x + (size_t)gr * F0))[kq];
        *(float4*)(&sx[r][kq << 2]) = v;
    }

    int tx = tid & 15, ty = tid >> 4;
    int c0 = tx * 4, r0 = ty * 4;
    float acc[4][4] = {};

    const float4* W4 = (const float4*)W1;
    float4* sW4 = (float4*)(&sW[0][0]);

    for (int p = 0; p < 2; ++p) {
        if (p) __syncthreads();                 // all reads of previous half done
        for (int i = tid; i < 1024; i += 256) sW4[i] = W4[p * 1024 + i];
        __syncthreads();
        int kbase = p * 64;
        for (int k = 0; k < 64; k += 4) {
            float a[4][4], b[4][4];
            #pragma unroll
            for (int rr = 0; rr < 4; ++rr)
                *(float4*)&a[rr][0] = *(const float4*)&sx[r0 + rr][kbase + k];
            #pragma unroll
            for (int j = 0; j < 4; ++j)
                *(float4*)&b[j][0] = *(const float4*)&sW[k + j][c0];
            #pragma unroll
            for (int j = 0; j < 4; ++j)
                #pragma unroll
                for (int rr = 0; rr < 4; ++rr)
                    #pragma unroll
                    for (int cc = 0; cc < 4; ++cc)
                        acc[rr][cc] += a[rr][j] * b[j][cc];
        }
    }

    #pragma unroll
    for (int rr = 0; rr < 4; ++rr) {
        int gr = row0 + r0 + rr;
        if (gr < N) {
            float s = dinv[gr];
            float4 o = make_float4(acc[rr][0] * s, acc[rr][1] * s, acc[rr][2] * s, acc[rr][3] * s);
            *(float4*)&xws1[(size_t)gr * F1 + c0] = o;
        }
    }
}

// ---------------- gather1: h1 = relu(dinv[d]*(sum_in xws1[s] + xws1[d]) + b1) ----------
__global__ __launch_bounds__(256) void gather1(const int* __restrict__ csr,
                                               const int* __restrict__ rowptr,
                                               const int* __restrict__ deg,
                                               const float* __restrict__ dinv,
                                               const float* __restrict__ xws1,
                                               const float* __restrict__ b1,
                                               float* __restrict__ h1, int N) {
    int wid = (blockIdx.x * 256 + threadIdx.x) >> 6;
    int lane = threadIdx.x & 63;
    if (wid >= N) return;
    int node = rfl(wid);
    int start = rfl(rowptr[node]);
    int cnt = rfl(deg[node]);
    float a0 = 0.f, a1 = 0.f, a2 = 0.f, a3 = 0.f;
    int j = 0;
    for (; j + 4 <= cnt; j += 4) {
        int s0 = rfl(csr[start + j]);
        int s1 = rfl(csr[start + j + 1]);
        int s2 = rfl(csr[start + j + 2]);
        int s3 = rfl(csr[start + j + 3]);
        a0 += xws1[(size_t)s0 * F1 + lane];
        a1 += xws1[(size_t)s1 * F1 + lane];
        a2 += xws1[(size_t)s2 * F1 + lane];
        a3 += xws1[(size_t)s3 * F1 + lane];
    }
    for (; j < cnt; ++j) {
        int s = rfl(csr[start + j]);
        a0 += xws1[(size_t)s * F1 + lane];
    }
    float acc = (a0 + a1) + (a2 + a3);
    float dd = dinv[node];
    float v = dd * (acc + xws1[(size_t)node * F1 + lane]) + b1[lane];
    h1[(size_t)node * F1 + lane] = fmaxf(v, 0.f);
}

// ---------------- GEMM2: xws2 = (h1 @ W2) * dinv[row]   [N,64]x[64,32] ----------------
__global__ __launch_bounds__(256) void gemm2(const float* __restrict__ h1,
                                             const float* __restrict__ W2,
                                             const float* __restrict__ dinv,
                                             float* __restrict__ xws2, int N) {
    __shared__ float sx[128][68];
    __shared__ float sW[64][32];
    int tid = threadIdx.x;
    int row0 = blockIdx.x * 128;

    for (int i = tid; i < 512; i += 256) ((float4*)&sW[0][0])[i] = ((const float4*)W2)[i];
    for (int i = tid; i < 2048; i += 256) {
        int r = i >> 4, kq = i & 15;
        int gr = row0 + r;
        float4 v = make_float4(0.f, 0.f, 0.f, 0.f);
        if (gr < N) v = ((const float4*)(h1 + (size_t)gr * F1))[kq];
        *(float4*)(&sx[r][kq << 2]) = v;
    }
    __syncthreads();

    int tx = tid & 7, ty = tid >> 3;
    int c0 = tx * 4, r0 = ty * 4;
    float acc[4][4] = {};
    for (int k = 0; k < 64; k += 4) {
        float a[4][4], b[4][4];
        #pragma unroll
        for (int rr = 0; rr < 4; ++rr)
            *(float4*)&a[rr][0] = *(const float4*)&sx[r0 + rr][k];
        #pragma unroll
        for (int j = 0; j < 4; ++j)
            *(float4*)&b[j][0] = *(const float4*)&sW[k + j][c0];
        #pragma unroll
        for (int j = 0; j < 4; ++j)
            #pragma unroll
            for (int rr = 0; rr < 4; ++rr)
                #pragma unroll
                for (int cc = 0; cc < 4; ++cc)
                    acc[rr][cc] += a[rr][j] * b[j][cc];
    }

    #pragma unroll
    for (int rr = 0; rr < 4; ++rr) {
        int gr = row0 + r0 + rr;
        if (gr < N) {
            float s = dinv[gr];
            float4 o = make_float4(acc[rr][0] * s, acc[rr][1] * s, acc[rr][2] * s, acc[rr][3] * s);
            *(float4*)&xws2[(size_t)gr * F2 + c0] = o;
        }
    }
}

// ---------------- gather2: 32 cols; wave halves process alternate edges ----------------
__global__ __launch_bounds__(256) void gather2(const int* __restrict__ csr,
                                               const int* __restrict__ rowptr,
                                               const int* __restrict__ deg,
                                               const float* __restrict__ dinv,
                                               const float* __restrict__ xws2,
                                               const float* __restrict__ b2,
                                               float* __restrict__ h2, int N) {
    int wid = (blockIdx.x * 256 + threadIdx.x) >> 6;
    int lane = threadIdx.x & 63;
    if (wid >= N) return;
    int node = rfl(wid);
    int start = rfl(rowptr[node]);
    int cnt = rfl(deg[node]);
    int c = lane & 31, half = lane >> 5;
    float a0 = 0.f, a1 = 0.f;
    int j = 0;
    for (; j + 4 <= cnt; j += 4) {
        int s0 = rfl(csr[start + j]);
        int s1 = rfl(csr[start + j + 1]);
        int s2 = rfl(csr[start + j + 2]);
        int s3 = rfl(csr[start + j + 3]);
        int sa = half ? s1 : s0;
        int sb = half ? s3 : s2;
        a0 += xws2[(size_t)sa * F2 + c];
        a1 += xws2[(size_t)sb * F2 + c];
    }
    for (; j + 2 <= cnt; j += 2) {
        int s0 = rfl(csr[start + j]);
        int s1 = rfl(csr[start + j + 1]);
        int sa = half ? s1 : s0;
        a0 += xws2[(size_t)sa * F2 + c];
    }
    if (j < cnt) {
        int s = rfl(csr[start + j]);
        if (half == 0) a0 += xws2[(size_t)s * F2 + c];
    }
    float acc = a0 + a1;
    acc += __shfl_down(acc, 32, 64);
    if (half == 0) {
        float dd = dinv[node];
        float v = dd * (acc + xws2[(size_t)node * F2 + c]) + b2[c];
        h2[(size_t)node * F2 + c] = fmaxf(v, 0.f);
    }
}

// ---------------- GEMM3: out = h2 @ Wl + bl   [N,32]x[32,128] ----------------
__global__ __launch_bounds__(256) void gemm3(const float* __restrict__ h2,
                                             const float* __restrict__ Wl,
                                             const float* __restrict__ bl,
                                             float* __restrict__ out, int N) {
    __shared__ float sx[64][36];
    __shared__ float sW[32][128];
    int tid = threadIdx.x;
    int row0 = blockIdx.x * 64;

    for (int i = tid; i < 1024; i += 256) ((float4*)&sW[0][0])[i] = ((const float4*)Wl)[i];
    for (int i = tid; i < 512; i += 256) {
        int r = i >> 3, kq = i & 7;
        int gr = row0 + r;
        float4 v = make_float4(0.f, 0.f, 0.f, 0.f);
        if (gr < N) v = ((const float4*)(h2 + (size_t)gr * F2))[kq];
        *(float4*)(&sx[r][kq << 2]) = v;
    }
    __syncthreads();

    int tx = tid & 15, ty = tid >> 4;
    int c0 = tx * 8, r0 = ty * 4;
    float acc[4][8] = {};
    for (int k = 0; k < 32; k += 4) {
        float a[4][4], b[4][8];
        #pragma unroll
        for (int rr = 0; rr < 4; ++rr)
            *(float4*)&a[rr][0] = *(const float4*)&sx[r0 + rr][k];
        #pragma unroll
        for (int j = 0; j < 4; ++j) {
            *(float4*)&b[j][0] = *(const float4*)&sW[k + j][c0];
            *(float4*)&b[j][4] = *(const float4*)&sW[k + j][c0 + 4];
        }
        #pragma unroll
        for (int j = 0; j < 4; ++j)
            #pragma unroll
            for (int rr = 0; rr < 4; ++rr)
                #pragma unroll
                for (int cc = 0; cc < 8; ++cc)
                    acc[rr][cc] += a[rr][j] * b[j][cc];
    }

    float4 bia0 = *(const float4*)&bl[c0];
    float4 bia1 = *(const float4*)&bl[c0 + 4];
    #pragma unroll
    for (int rr = 0; rr < 4; ++rr) {
        int gr = row0 + r0 + rr;
        if (gr < N) {
            float4 o0 = make_float4(acc[rr][0] + bia0.x, acc[rr][1] + bia0.y,
                                    acc[rr][2] + bia0.z, acc[rr][3] + bia0.w);
            float4 o1 = make_float4(acc[rr][4] + bia1.x, acc[rr][5] + bia1.y,
                                    acc[rr][6] + bia1.z, acc[rr][7] + bia1.w);
            *(float4*)&out[(size_t)gr * F0 + c0] = o0;
            *(float4*)&out[(size_t)gr * F0 + c0 + 4] = o1;
        }
    }
}

extern "C" void kernel_launch(void* const* d_in, const int* in_sizes, int n_in,
                              void* d_out, int out_size, void* d_ws, size_t ws_size,
                              hipStream_t stream) {
    const float* x  = (const float*)d_in[0];
    const int*   ei = (const int*)d_in[1];
    const float* W1 = (const float*)d_in[2];
    const float* b1 = (const float*)d_in[3];
    const float* W2 = (const float*)d_in[4];
    const float* b2 = (const float*)d_in[5];
    const float* Wl = (const float*)d_in[6];
    const float* bl = (const float*)d_in[7];
    float* out = (float*)d_out;

    const int N = in_sizes[0] / F0;   // 50000
    const int E = in_sizes[1] / 2;    // 800000
    const int* src = ei;
    const int* dst = ei + E;
    const int NB = (N + 255) / 256;   // 196

    char* ws = (char*)d_ws;
    size_t off = 0;
    auto alloc = [&](size_t bytes) {
        void* p = ws + off;
        off += (bytes + 255) & ~(size_t)255;
        return p;
    };
    int*   deg    = (int*)alloc((size_t)N * 4);
    float* dinv   = (float*)alloc((size_t)N * 4);
    int*   rowptr = (int*)alloc((size_t)N * 4);
    int*   cursor = (int*)alloc((size_t)N * 4);
    int*   bsum   = (int*)alloc((size_t)NB * 4);
    int*   boff   = (int*)alloc((size_t)NB * 4);
    int*   csr    = (int*)alloc((size_t)E * 4);
    float* xws1   = (float*)alloc((size_t)N * F1 * 4);
    float* h1     = (float*)alloc((size_t)N * F1 * 4);
    float* xws2   = xws1;   // dead after gather1
    float* h2     = h1;     // dead after gemm2

    hipMemsetAsync(deg, 0, (size_t)N * 4, stream);
    deg_count<<<(E + 255) / 256, 256, 0, stream>>>(dst, deg, E);
    scan1<<<NB, 256, 0, stream>>>(deg, dinv, rowptr, bsum, N);
    scan2<<<1, 256, 0, stream>>>(bsum, boff, NB);
    scan3<<<NB, 256, 0, stream>>>(rowptr, boff, cursor, N);
    bucket<<<(E + 255) / 256, 256, 0, stream>>>(src, dst, cursor, csr, E);

    gemm1<<<(N + 63) / 64, 256, 0, stream>>>(x, W1, dinv, xws1, N);
    gather1<<<(N + 3) / 4, 256, 0, stream>>>(csr, rowptr, deg, dinv, xws1, b1, h1, N);

    gemm2<<<(N + 127) / 128, 256, 0, stream>>>(h1, W2, dinv, xws2, N);
    gather2<<<(N + 3) / 4, 256, 0, stream>>>(csr, rowptr, deg, dinv, xws2, b2, h2, N);

    gemm3<<<(N + 63) / 64, 256, 0, stream>>>(h2, Wl, bl, out, N);
}

// Round 8
// 273.814 us; speedup vs baseline: 2.1067x; 2.1067x over previous
//
#include <hip/hip_runtime.h>

#define F0 128
#define F1 64
#define F2 32

__device__ __forceinline__ int rfl(int v) { return __builtin_amdgcn_readfirstlane(v); }

// ---------------- degree ----------------
__global__ void deg_count(const int* __restrict__ dst, int* __restrict__ deg, int E) {
    int e = blockIdx.x * blockDim.x + threadIdx.x;
    if (e < E) atomicAdd(&deg[dst[e]], 1);
}

// ---------------- scan (3 kernels), dinv fused into scan1 ----------------
__global__ void scan1(const int* __restrict__ deg, float* __restrict__ dinv,
                      int* __restrict__ rowptr, int* __restrict__ bsum, int N) {
    __shared__ int s[256];
    int i = blockIdx.x * 256 + threadIdx.x;
    int v = (i < N) ? deg[i] : 0;
    if (i < N) dinv[i] = rsqrtf((float)(v + 1));  // +1 self-loop
    s[threadIdx.x] = v;
    __syncthreads();
    for (int off = 1; off < 256; off <<= 1) {
        int t = 0;
        if (threadIdx.x >= off) t = s[threadIdx.x - off];
        __syncthreads();
        if (threadIdx.x >= off) s[threadIdx.x] += t;
        __syncthreads();
    }
    if (i < N) rowptr[i] = s[threadIdx.x] - v;
    if (threadIdx.x == 255) bsum[blockIdx.x] = s[255];
}

__global__ void scan2(int* __restrict__ bsum, int* __restrict__ boff, int nb) {
    __shared__ int s[256];
    int v = (threadIdx.x < nb) ? bsum[threadIdx.x] : 0;
    s[threadIdx.x] = v;
    __syncthreads();
    for (int off = 1; off < 256; off <<= 1) {
        int t = 0;
        if (threadIdx.x >= off) t = s[threadIdx.x - off];
        __syncthreads();
        if (threadIdx.x >= off) s[threadIdx.x] += t;
        __syncthreads();
    }
    if (threadIdx.x < nb) boff[threadIdx.x] = s[threadIdx.x] - v;
}

// scan3 also copies the finalized rowptr into cursor (no d2d memcpy in kernel_launch)
__global__ void scan3(int* __restrict__ rowptr, const int* __restrict__ boff,
                      int* __restrict__ cursor, int N) {
    int i = blockIdx.x * 256 + threadIdx.x;
    if (i < N) {
        int v = rowptr[i] + boff[blockIdx.x];
        rowptr[i] = v;
        cursor[i] = v;
    }
}

// ---------------- bucket: cursor pre-initialized to rowptr ----------------
__global__ void bucket(const int* __restrict__ src, const int* __restrict__ dst,
                       int* __restrict__ cursor, int* __restrict__ csr, int E) {
    int e = blockIdx.x * 256 + threadIdx.x;
    if (e < E) {
        int pos = atomicAdd(&cursor[dst[e]], 1);
        csr[pos] = src[e];
    }
}

// ---------------- GEMM1: xws1 = (x @ W1) * dinv[row]   [N,128]x[128,64] ----------------
// 64x64 tile, 4x4 per thread. k-loop bound `kb` is a RUNTIME arg so the compiler
// cannot fully unroll (round-5 post-mortem: full unroll -> 256 VGPR -> 750 MB spill).
__global__ __launch_bounds__(256) void gemm1(const float* __restrict__ x,
                                             const float* __restrict__ W1,
                                             const float* __restrict__ dinv,
                                             float* __restrict__ xws1, int N, int kb) {
    __shared__ float sx[64][132];   // +4 pad: bank-safe, 16B-aligned rows
    __shared__ float sW[64][64];    // one K-half of W1
    int tid = threadIdx.x;
    int row0 = blockIdx.x * 64;

    for (int i = tid; i < 2048; i += 256) {
        int r = i >> 5, kq = i & 31;
        int gr = row0 + r;
        float4 v = make_float4(0.f, 0.f, 0.f, 0.f);
        if (gr < N) v = ((const float4*)(x + (size_t)gr * F0))[kq];
        *(float4*)(&sx[r][kq << 2]) = v;
    }

    int tx = tid & 15, ty = tid >> 4;
    int c0 = tx * 4, r0 = ty * 4;
    float acc[4][4] = {};

    const float4* W4 = (const float4*)W1;
    float4* sW4 = (float4*)(&sW[0][0]);

    for (int p = 0; p < 2; ++p) {
        if (p) __syncthreads();
        for (int i = tid; i < 1024; i += 256) sW4[i] = W4[p * 1024 + i];
        __syncthreads();
        int kbase = p * 64;
        for (int k = 0; k < kb; k += 4) {   // kb=64 at runtime: no full unroll
            float a[4][4], b[4][4];
            #pragma unroll
            for (int rr = 0; rr < 4; ++rr)
                *(float4*)&a[rr][0] = *(const float4*)&sx[r0 + rr][kbase + k];
            #pragma unroll
            for (int j = 0; j < 4; ++j)
                *(float4*)&b[j][0] = *(const float4*)&sW[k + j][c0];
            #pragma unroll
            for (int j = 0; j < 4; ++j)
                #pragma unroll
                for (int rr = 0; rr < 4; ++rr)
                    #pragma unroll
                    for (int cc = 0; cc < 4; ++cc)
                        acc[rr][cc] += a[rr][j] * b[j][cc];
        }
    }

    #pragma unroll
    for (int rr = 0; rr < 4; ++rr) {
        int gr = row0 + r0 + rr;
        if (gr < N) {
            float s = dinv[gr];
            float4 o = make_float4(acc[rr][0] * s, acc[rr][1] * s, acc[rr][2] * s, acc[rr][3] * s);
            *(float4*)&xws1[(size_t)gr * F1 + c0] = o;
        }
    }
}

// ---------------- gather1: h1 = relu(dinv[d]*(sum_in xws1[s] + xws1[d]) + b1) ----------
__global__ __launch_bounds__(256) void gather1(const int* __restrict__ csr,
                                               const int* __restrict__ rowptr,
                                               const int* __restrict__ deg,
                                               const float* __restrict__ dinv,
                                               const float* __restrict__ xws1,
                                               const float* __restrict__ b1,
                                               float* __restrict__ h1, int N) {
    int wid = (blockIdx.x * 256 + threadIdx.x) >> 6;
    int lane = threadIdx.x & 63;
    if (wid >= N) return;
    int node = rfl(wid);
    int start = rfl(rowptr[node]);
    int cnt = rfl(deg[node]);
    float a0 = 0.f, a1 = 0.f, a2 = 0.f, a3 = 0.f;
    int j = 0;
    for (; j + 4 <= cnt; j += 4) {
        int s0 = rfl(csr[start + j]);
        int s1 = rfl(csr[start + j + 1]);
        int s2 = rfl(csr[start + j + 2]);
        int s3 = rfl(csr[start + j + 3]);
        a0 += xws1[(size_t)s0 * F1 + lane];
        a1 += xws1[(size_t)s1 * F1 + lane];
        a2 += xws1[(size_t)s2 * F1 + lane];
        a3 += xws1[(size_t)s3 * F1 + lane];
    }
    for (; j < cnt; ++j) {
        int s = rfl(csr[start + j]);
        a0 += xws1[(size_t)s * F1 + lane];
    }
    float acc = (a0 + a1) + (a2 + a3);
    float dd = dinv[node];
    float v = dd * (acc + xws1[(size_t)node * F1 + lane]) + b1[lane];
    h1[(size_t)node * F1 + lane] = fmaxf(v, 0.f);
}

// ---------------- GEMM2: xws2 = (h1 @ W2) * dinv[row]   [N,64]x[64,32] ----------------
__global__ __launch_bounds__(256) void gemm2(const float* __restrict__ h1,
                                             const float* __restrict__ W2,
                                             const float* __restrict__ dinv,
                                             float* __restrict__ xws2, int N, int kb) {
    __shared__ float sx[128][68];
    __shared__ float sW[64][32];
    int tid = threadIdx.x;
    int row0 = blockIdx.x * 128;

    for (int i = tid; i < 512; i += 256) ((float4*)&sW[0][0])[i] = ((const float4*)W2)[i];
    for (int i = tid; i < 2048; i += 256) {
        int r = i >> 4, kq = i & 15;
        int gr = row0 + r;
        float4 v = make_float4(0.f, 0.f, 0.f, 0.f);
        if (gr < N) v = ((const float4*)(h1 + (size_t)gr * F1))[kq];
        *(float4*)(&sx[r][kq << 2]) = v;
    }
    __syncthreads();

    int tx = tid & 7, ty = tid >> 3;
    int c0 = tx * 4, r0 = ty * 4;
    float acc[4][4] = {};
    for (int k = 0; k < kb; k += 4) {   // kb=64 at runtime
        float a[4][4], b[4][4];
        #pragma unroll
        for (int rr = 0; rr < 4; ++rr)
            *(float4*)&a[rr][0] = *(const float4*)&sx[r0 + rr][k];
        #pragma unroll
        for (int j = 0; j < 4; ++j)
            *(float4*)&b[j][0] = *(const float4*)&sW[k + j][c0];
        #pragma unroll
        for (int j = 0; j < 4; ++j)
            #pragma unroll
            for (int rr = 0; rr < 4; ++rr)
                #pragma unroll
                for (int cc = 0; cc < 4; ++cc)
                    acc[rr][cc] += a[rr][j] * b[j][cc];
    }

    #pragma unroll
    for (int rr = 0; rr < 4; ++rr) {
        int gr = row0 + r0 + rr;
        if (gr < N) {
            float s = dinv[gr];
            float4 o = make_float4(acc[rr][0] * s, acc[rr][1] * s, acc[rr][2] * s, acc[rr][3] * s);
            *(float4*)&xws2[(size_t)gr * F2 + c0] = o;
        }
    }
}

// ---------------- gather2: 32 cols; wave halves process alternate edges ----------------
__global__ __launch_bounds__(256) void gather2(const int* __restrict__ csr,
                                               const int* __restrict__ rowptr,
                                               const int* __restrict__ deg,
                                               const float* __restrict__ dinv,
                                               const float* __restrict__ xws2,
                                               const float* __restrict__ b2,
                                               float* __restrict__ h2, int N) {
    int wid = (blockIdx.x * 256 + threadIdx.x) >> 6;
    int lane = threadIdx.x & 63;
    if (wid >= N) return;
    int node = rfl(wid);
    int start = rfl(rowptr[node]);
    int cnt = rfl(deg[node]);
    int c = lane & 31, half = lane >> 5;
    float a0 = 0.f, a1 = 0.f;
    int j = 0;
    for (; j + 4 <= cnt; j += 4) {
        int s0 = rfl(csr[start + j]);
        int s1 = rfl(csr[start + j + 1]);
        int s2 = rfl(csr[start + j + 2]);
        int s3 = rfl(csr[start + j + 3]);
        int sa = half ? s1 : s0;
        int sb = half ? s3 : s2;
        a0 += xws2[(size_t)sa * F2 + c];
        a1 += xws2[(size_t)sb * F2 + c];
    }
    for (; j + 2 <= cnt; j += 2) {
        int s0 = rfl(csr[start + j]);
        int s1 = rfl(csr[start + j + 1]);
        int sa = half ? s1 : s0;
        a0 += xws2[(size_t)sa * F2 + c];
    }
    if (j < cnt) {
        int s = rfl(csr[start + j]);
        if (half == 0) a0 += xws2[(size_t)s * F2 + c];
    }
    float acc = a0 + a1;
    acc += __shfl_down(acc, 32, 64);
    if (half == 0) {
        float dd = dinv[node];
        float v = dd * (acc + xws2[(size_t)node * F2 + c]) + b2[c];
        h2[(size_t)node * F2 + c] = fmaxf(v, 0.f);
    }
}

// ---------------- GEMM3: out = h2 @ Wl + bl   [N,32]x[32,128] ----------------
__global__ __launch_bounds__(256) void gemm3(const float* __restrict__ h2,
                                             const float* __restrict__ Wl,
                                             const float* __restrict__ bl,
                                             float* __restrict__ out, int N, int kb) {
    __shared__ float sx[64][36];
    __shared__ float sW[32][128];
    int tid = threadIdx.x;
    int row0 = blockIdx.x * 64;

    for (int i = tid; i < 1024; i += 256) ((float4*)&sW[0][0])[i] = ((const float4*)Wl)[i];
    for (int i = tid; i < 512; i += 256) {
        int r = i >> 3, kq = i & 7;
        int gr = row0 + r;
        float4 v = make_float4(0.f, 0.f, 0.f, 0.f);
        if (gr < N) v = ((const float4*)(h2 + (size_t)gr * F2))[kq];
        *(float4*)(&sx[r][kq << 2]) = v;
    }
    __syncthreads();

    int tx = tid & 15, ty = tid >> 4;
    int c0 = tx * 8, r0 = ty * 4;
    float acc[4][8] = {};
    for (int k = 0; k < kb; k += 4) {   // kb=32 at runtime
        float a[4][4], b[4][8];
        #pragma unroll
        for (int rr = 0; rr < 4; ++rr)
            *(float4*)&a[rr][0] = *(const float4*)&sx[r0 + rr][k];
        #pragma unroll
        for (int j = 0; j < 4; ++j) {
            *(float4*)&b[j][0] = *(const float4*)&sW[k + j][c0];
            *(float4*)&b[j][4] = *(const float4*)&sW[k + j][c0 + 4];
        }
        #pragma unroll
        for (int j = 0; j < 4; ++j)
            #pragma unroll
            for (int rr = 0; rr < 4; ++rr)
                #pragma unroll
                for (int cc = 0; cc < 8; ++cc)
                    acc[rr][cc] += a[rr][j] * b[j][cc];
    }

    float4 bia0 = *(const float4*)&bl[c0];
    float4 bia1 = *(const float4*)&bl[c0 + 4];
    #pragma unroll
    for (int rr = 0; rr < 4; ++rr) {
        int gr = row0 + r0 + rr;
        if (gr < N) {
            float4 o0 = make_float4(acc[rr][0] + bia0.x, acc[rr][1] + bia0.y,
                                    acc[rr][2] + bia0.z, acc[rr][3] + bia0.w);
            float4 o1 = make_float4(acc[rr][4] + bia1.x, acc[rr][5] + bia1.y,
                                    acc[rr][6] + bia1.z, acc[rr][7] + bia1.w);
            *(float4*)&out[(size_t)gr * F0 + c0] = o0;
            *(float4*)&out[(size_t)gr * F0 + c0 + 4] = o1;
        }
    }
}

extern "C" void kernel_launch(void* const* d_in, const int* in_sizes, int n_in,
                              void* d_out, int out_size, void* d_ws, size_t ws_size,
                              hipStream_t stream) {
    const float* x  = (const float*)d_in[0];
    const int*   ei = (const int*)d_in[1];
    const float* W1 = (const float*)d_in[2];
    const float* b1 = (const float*)d_in[3];
    const float* W2 = (const float*)d_in[4];
    const float* b2 = (const float*)d_in[5];
    const float* Wl = (const float*)d_in[6];
    const float* bl = (const float*)d_in[7];
    float* out = (float*)d_out;

    const int N = in_sizes[0] / F0;   // 50000
    const int E = in_sizes[1] / 2;    // 800000
    const int* src = ei;
    const int* dst = ei + E;
    const int NB = (N + 255) / 256;   // 196

    char* ws = (char*)d_ws;
    size_t off = 0;
    auto alloc = [&](size_t bytes) {
        void* p = ws + off;
        off += (bytes + 255) & ~(size_t)255;
        return p;
    };
    int*   deg    = (int*)alloc((size_t)N * 4);
    float* dinv   = (float*)alloc((size_t)N * 4);
    int*   rowptr = (int*)alloc((size_t)N * 4);
    int*   cursor = (int*)alloc((size_t)N * 4);
    int*   bsum   = (int*)alloc((size_t)NB * 4);
    int*   boff   = (int*)alloc((size_t)NB * 4);
    int*   csr    = (int*)alloc((size_t)E * 4);
    float* xws1   = (float*)alloc((size_t)N * F1 * 4);
    float* h1     = (float*)alloc((size_t)N * F1 * 4);
    float* xws2   = xws1;   // dead after gather1
    float* h2     = h1;     // dead after gemm2

    hipMemsetAsync(deg, 0, (size_t)N * 4, stream);
    deg_count<<<(E + 255) / 256, 256, 0, stream>>>(dst, deg, E);
    scan1<<<NB, 256, 0, stream>>>(deg, dinv, rowptr, bsum, N);
    scan2<<<1, 256, 0, stream>>>(bsum, boff, NB);
    scan3<<<NB, 256, 0, stream>>>(rowptr, boff, cursor, N);
    bucket<<<(E + 255) / 256, 256, 0, stream>>>(src, dst, cursor, csr, E);

    gemm1<<<(N + 63) / 64, 256, 0, stream>>>(x, W1, dinv, xws1, N, 64);
    gather1<<<(N + 3) / 4, 256, 0, stream>>>(csr, rowptr, deg, dinv, xws1, b1, h1, N);

    gemm2<<<(N + 127) / 128, 256, 0, stream>>>(h1, W2, dinv, xws2, N, 64);
    gather2<<<(N + 3) / 4, 256, 0, stream>>>(csr, rowptr, deg, dinv, xws2, b2, h2, N);

    gemm3<<<(N + 63) / 64, 256, 0, stream>>>(h2, Wl, bl, out, N, 32);
}